// Round 13
// baseline (179.116 us; speedup 1.0000x reference)
//
#include <hip/hip_runtime.h>
#include <hip/hip_bf16.h>

#define SS 2048
#define HH 1024
#define NHH 16
#define HDD 64

using f32x4  = __attribute__((ext_vector_type(4))) float;
using bf16x8 = __attribute__((ext_vector_type(8))) short;

#if __has_builtin(__builtin_amdgcn_exp2f)
#define EXP2F __builtin_amdgcn_exp2f
#else
#define EXP2F exp2f
#endif

__device__ __forceinline__ unsigned short f2bf(float f) {
    unsigned u = __builtin_bit_cast(unsigned, f);
    unsigned r = u + 0x7FFFu + ((u >> 16) & 1u);
    return (unsigned short)(r >> 16);
}

__device__ __forceinline__ unsigned bfround(float f) {
    unsigned u = __builtin_bit_cast(unsigned, f);
    return u + 0x7FFFu + ((u >> 16) & 1u);
}
// low16 = bf16(a), high16 = bf16(b) — one v_perm_b32
__device__ __forceinline__ unsigned pack2bf(float a, float b) {
    return __builtin_amdgcn_perm(bfround(b), bfround(a), 0x07060302u);
}

__device__ __forceinline__ void tetra(float t, float* c) {
    float a = 1.f / (1.f + __expf(-t));
    float na = 1.f - a;
    float nei = 1.f - (a + na);
    nei = fminf(fmaxf(nei, 0.f), 1.f);
    c[0] = a; c[1] = na; c[2] = a * na; c[3] = nei;
}

// ---------------- cvt: fp32 -> bf16 for x, Wv, Wo; blocks >=2048 gather Wsel ----------------
__global__ __launch_bounds__(256) void cvt_kernel(
    const float* __restrict__ x, const float* __restrict__ Wv, const float* __restrict__ Wo,
    const float* __restrict__ Wq, const float* __restrict__ Wk,
    const float* __restrict__ bq, const float* __restrict__ bk,
    unsigned short* __restrict__ xb, unsigned short* __restrict__ Wvb, unsigned short* __restrict__ Wob,
    unsigned short* __restrict__ wselb, float* __restrict__ bselws)
{
    if (blockIdx.x >= 2048) {
        int n = blockIdx.x - 2048;
        int h = n >> 2, q = n & 3;
        int rowIdx = h * HDD + ((q & 1) ? 2 : 0);
        const float* src  = (q & 2) ? Wk : Wq;
        const float* bsrc = (q & 2) ? bk : bq;
        int t = threadIdx.x;
        float4 v = *(const float4*)(src + (size_t)rowIdx * HH + t * 4);
        uint2 pk;
        pk.x = pack2bf(v.x, v.y);
        pk.y = pack2bf(v.z, v.w);
        *(uint2*)(wselb + (size_t)n * HH + t * 4) = pk;
        if (t == 0) bselws[n] = bsrc[rowIdx];
        return;
    }
    size_t gid = (size_t)blockIdx.x * 256 + threadIdx.x;
    size_t base = gid * 8;
    {
        float4 a = *(const float4*)(x + base);
        float4 b = *(const float4*)(x + base + 4);
        uint4 pk;
        pk.x = pack2bf(a.x, a.y);
        pk.y = pack2bf(a.z, a.w);
        pk.z = pack2bf(b.x, b.y);
        pk.w = pack2bf(b.z, b.w);
        *(uint4*)(xb + base) = pk;
    }
    if (base < 1048576) {
        float4 a = *(const float4*)(Wv + base);
        float4 b = *(const float4*)(Wv + base + 4);
        uint4 pk;
        pk.x = pack2bf(a.x, a.y);
        pk.y = pack2bf(a.z, a.w);
        pk.z = pack2bf(b.x, b.y);
        pk.w = pack2bf(b.z, b.w);
        *(uint4*)(Wvb + base) = pk;
        a = *(const float4*)(Wo + base);
        b = *(const float4*)(Wo + base + 4);
        pk.x = pack2bf(a.x, a.y);
        pk.y = pack2bf(a.z, a.w);
        pk.z = pack2bf(b.x, b.y);
        pk.w = pack2bf(b.z, b.w);
        *(uint4*)(Wob + base) = pk;
    }
}

// ---------------- GEMM body: 64x64 tile, 4 waves x 32x32, BK=64, reg-prefetch ----------------
// OUT_MODE 0: fp32 row-major C. OUT_MODE 2: bf16 transposed into Vt[(bh*64+d)*SS + s].
template<int OUT_MODE>
__device__ __forceinline__ void gemm_body(unsigned char* smem,
    const unsigned short* __restrict__ A, const unsigned short* __restrict__ Bw,
    const float* __restrict__ bias, void* __restrict__ Cout, int bx, int by)
{
    auto As = (unsigned short (*)[72])smem;            // [64][72] = 9216 B
    auto Bs = (unsigned short (*)[72])(smem + 9216);   // [64][72]
    int tid = threadIdx.x;
    int wave = tid >> 6, lane = tid & 63;
    int l15 = lane & 15, l16 = lane >> 4;
    int wm = wave >> 1, wn = wave & 1;
    int m0 = by * 64, n0 = bx * 64;

    int lr = tid >> 2, lseg = (tid & 3) * 16;   // 4 thr/row x 16 shorts = full 64
    const unsigned short* Ap = A + (size_t)(m0 + lr) * HH + lseg;
    const unsigned short* Bp = Bw + (size_t)(n0 + lr) * HH + lseg;

    f32x4 acc[2][2] = {};

    uint4 a0 = *(const uint4*)(Ap);
    uint4 a1 = *(const uint4*)(Ap + 8);
    uint4 b0 = *(const uint4*)(Bp);
    uint4 b1 = *(const uint4*)(Bp + 8);

    for (int k0 = 0; k0 < HH; k0 += 64) {
        __syncthreads();
        *(uint4*)&As[lr][lseg]     = a0;
        *(uint4*)&As[lr][lseg + 8] = a1;
        *(uint4*)&Bs[lr][lseg]     = b0;
        *(uint4*)&Bs[lr][lseg + 8] = b1;
        __syncthreads();

        int kn = (k0 + 64) & (HH - 1);
        uint4 na0 = *(const uint4*)(Ap + kn);
        uint4 na1 = *(const uint4*)(Ap + kn + 8);
        uint4 nb0 = *(const uint4*)(Bp + kn);
        uint4 nb1 = *(const uint4*)(Bp + kn + 8);

        #pragma unroll
        for (int kk = 0; kk < 64; kk += 32) {
            bf16x8 af[2], bfr[2];
            #pragma unroll
            for (int mi = 0; mi < 2; mi++)
                af[mi] = *(const bf16x8*)&As[wm * 32 + mi * 16 + l15][kk + l16 * 8];
            #pragma unroll
            for (int ni = 0; ni < 2; ni++)
                bfr[ni] = *(const bf16x8*)&Bs[wn * 32 + ni * 16 + l15][kk + l16 * 8];
            #pragma unroll
            for (int mi = 0; mi < 2; mi++)
                #pragma unroll
                for (int ni = 0; ni < 2; ni++)
                    acc[mi][ni] = __builtin_amdgcn_mfma_f32_16x16x32_bf16(af[mi], bfr[ni], acc[mi][ni], 0, 0, 0);
        }
        a0 = na0; a1 = na1; b0 = nb0; b1 = nb1;
    }

    float bv[2];
    #pragma unroll
    for (int ni = 0; ni < 2; ni++)
        bv[ni] = bias[n0 + wn * 32 + ni * 16 + l15];

    #pragma unroll
    for (int mi = 0; mi < 2; mi++) {
        #pragma unroll
        for (int ni = 0; ni < 2; ni++) {
            int n = n0 + wn * 32 + ni * 16 + l15;
            if (OUT_MODE == 0) {
                #pragma unroll
                for (int r = 0; r < 4; r++) {
                    int m = m0 + wm * 32 + mi * 16 + l16 * 4 + r;
                    ((float*)Cout)[(size_t)m * HH + n] = acc[mi][ni][r] + bv[ni];
                }
            } else {
                int m = m0 + wm * 32 + mi * 16 + l16 * 4;
                int b = m >> 11, s = m & 2047;
                int h = n >> 6, d = n & 63;
                uint2 pk;
                pk.x = pack2bf(acc[mi][ni][0] + bv[ni], acc[mi][ni][1] + bv[ni]);
                pk.y = pack2bf(acc[mi][ni][2] + bv[ni], acc[mi][ni][3] + bv[ni]);
                *(uint2*)((unsigned short*)Cout + ((size_t)((b * NHH + h) * HDD + d)) * SS + s) = pk;
            }
        }
    }
}

// ---------------- qk body (R8 config: 32 m-rows, BK=64, exp2 scales) ----------------
__device__ __forceinline__ void qk_body(unsigned char* smem,
    const unsigned short* __restrict__ xb, const unsigned short* __restrict__ wselb,
    const float* __restrict__ bselws,
    unsigned short* __restrict__ qfb, unsigned short* __restrict__ kfb, int blk)
{
    auto xs = (unsigned short (*)[72])smem;             // [32][72]  (4608 B)
    auto ws = (unsigned short (*)[72])(smem + 4608);    // [64][72]  (9216 B)
    auto ys = (float (*)[68])(smem + 13824);            // [32][68]  (8704 B)
    int tid = threadIdx.x;
    int wave = tid >> 6, lane = tid & 63;
    int l15 = lane & 15, l16 = lane >> 4;
    int m0 = blk * 32;
    int n0w = wave * 16;

    int xr = tid >> 3, xseg = (tid & 7) * 8;
    int wr = tid >> 2, wseg = (tid & 3) * 16;
    const unsigned short* xp = xb + (size_t)(m0 + xr) * HH + xseg;
    const unsigned short* wp = wselb + (size_t)wr * HH + wseg;

    f32x4 acc[2] = {};

    uint4 xv  = *(const uint4*)(xp);
    uint4 wv0 = *(const uint4*)(wp);
    uint4 wv1 = *(const uint4*)(wp + 8);

    for (int k0 = 0; k0 < HH; k0 += 64) {
        __syncthreads();
        *(uint4*)&xs[xr][xseg] = xv;
        *(uint4*)&ws[wr][wseg]     = wv0;
        *(uint4*)&ws[wr][wseg + 8] = wv1;
        __syncthreads();

        int kn = (k0 + 64) & (HH - 1);
        uint4 nxv  = *(const uint4*)(xp + kn);
        uint4 nwv0 = *(const uint4*)(wp + kn);
        uint4 nwv1 = *(const uint4*)(wp + kn + 8);

        #pragma unroll
        for (int kk = 0; kk < 64; kk += 32) {
            bf16x8 bfr = *(const bf16x8*)&ws[n0w + l15][kk + l16 * 8];
            #pragma unroll
            for (int mi = 0; mi < 2; mi++) {
                bf16x8 af = *(const bf16x8*)&xs[mi * 16 + l15][kk + l16 * 8];
                acc[mi] = __builtin_amdgcn_mfma_f32_16x16x32_bf16(af, bfr, acc[mi], 0, 0, 0);
            }
        }
        xv = nxv; wv0 = nwv0; wv1 = nwv1;
    }

    float bias = bselws[n0w + l15];
    __syncthreads();
    #pragma unroll
    for (int mi = 0; mi < 2; mi++)
        #pragma unroll
        for (int r = 0; r < 4; r++)
            ys[mi * 16 + l16 * 4 + r][n0w + l15] = acc[mi][r] + bias;
    __syncthreads();

    #pragma unroll
    for (int pass = 0; pass < 2; pass++) {
        int ml = tid & 31;
        int h = (tid >> 5) + pass * 8;
        float4 y4 = *(const float4*)&ys[ml][h * 4];
        float qa[4], qb2[4], ka[4], kb2[4];
        tetra(y4.x, qa);
        tetra(y4.y, qb2);
        tetra(y4.z, ka);
        tetra(y4.w, kb2);
        int m = m0 + ml, b = m >> 11, s = m & 2047;
        size_t base = ((size_t)(b * NHH + h) * SS + s) * 8;
        const float sA = 0.18033688011112042f;   // 0.125 * log2(e)
        const float sB = 0.14426950408889634f;   // 0.1   * log2(e)
        uint4 qp, kp;
        qp.x = pack2bf(qa[0] * sA, qa[1] * sA);
        qp.y = pack2bf(qa[2] * sA, qa[3] * sA);
        qp.z = pack2bf(qb2[0] * sB, qb2[1] * sB);
        qp.w = pack2bf(qb2[2] * sB, qb2[3] * sB);
        kp.x = pack2bf(ka[0], ka[1]);
        kp.y = pack2bf(ka[2], ka[3]);
        kp.z = pack2bf(kb2[0], kb2[1]);
        kp.w = pack2bf(kb2[2], kb2[3]);
        *(uint4*)(qfb + base) = qp;
        *(uint4*)(kfb + base) = kp;
    }
}

// ---------------- fused mid kernel: blocks 0-1023 = V-GEMM (64x64), 1024-1151 = qk ----------------
__global__ __launch_bounds__(256) void fused_mid(
    const unsigned short* __restrict__ xb,
    const unsigned short* __restrict__ Wvb, const float* __restrict__ bv,
    unsigned short* __restrict__ Vt,
    const unsigned short* __restrict__ wselb, const float* __restrict__ bselws,
    unsigned short* __restrict__ qfb, unsigned short* __restrict__ kfb)
{
    __shared__ __align__(16) unsigned char smem[22528];
    int id = blockIdx.x;
    if (id < 1024)
        gemm_body<2>(smem, xb, Wvb, bv, Vt, id & 15, id >> 4);
    else
        qk_body(smem, xb, wselb, bselws, qfb, kfb, id - 1024);
}

// ---------------- standalone O-projection GEMM (64x64 tiles) ----------------
__global__ __launch_bounds__(256) void gemm_out(
    const unsigned short* __restrict__ A, const unsigned short* __restrict__ Bw,
    const float* __restrict__ bias, float* __restrict__ Cout)
{
    __shared__ __align__(16) unsigned char smem[22528];
    gemm_body<0>(smem, A, Bw, bias, Cout, blockIdx.x, blockIdx.y);
}

// ---------------- MFMA flash attention (R10-measured config: 4 waves x 16 q) ----------------
// Block: one (b,h), 64 q. Tiles of 64 t. grid (32, 32) = 1024 blocks = 4 blocks/CU.
__global__ __launch_bounds__(256) void attn_mfma(
    const unsigned short* __restrict__ qfb, const unsigned short* __restrict__ kfb,
    const unsigned short* __restrict__ Vt, unsigned short* __restrict__ attnb)
{
    __shared__ unsigned short vt[64][72];       // V^T tile [d][t]
    __shared__ unsigned short ps[4][16][72];    // per-wave P [q][t]

    int tid = threadIdx.x;
    int wave = tid >> 6, lane = tid & 63;
    int l15 = lane & 15, l16 = lane >> 4;
    int bh = blockIdx.y, b = bh >> 4, h = bh & 15;
    int s0 = blockIdx.x * 64 + wave * 16;       // this wave's 16 q

    bf16x8 bfq = {0,0,0,0,0,0,0,0};
    if (l16 == 0)
        bfq = *(const bf16x8*)(qfb + ((size_t)bh * SS + s0 + l15) * 8);

    const short oneb = 0x3F80;                  // bf16 1.0
    bf16x8 ones = {oneb,oneb,oneb,oneb,oneb,oneb,oneb,oneb};

    const unsigned short* kfA = kfb + ((size_t)bh * SS + l15) * 8;
    int vd = tid >> 2, vseg = (tid & 3) * 16;
    const unsigned short* vsrc = Vt + ((size_t)bh * HDD + vd) * SS + vseg;

    f32x4 acc[4] = {};     // [nd] -> 16 q x 16 d each
    f32x4 accl = {};       // l via ones-column MFMA; row layout == acc rows

    // prefetch tile 0
    uint4 sv0 = *(const uint4*)(vsrc);
    uint4 sv1 = *(const uint4*)(vsrc + 8);
    bf16x8 kfr[4];
    #pragma unroll
    for (int tb = 0; tb < 4; tb++)
        kfr[tb] = *(const bf16x8*)(kfA + (size_t)(tb * 16) * 8);

    for (int t0 = 0; t0 < SS; t0 += 64) {
        __syncthreads();
        *(uint4*)&vt[vd][vseg]     = sv0;
        *(uint4*)&vt[vd][vseg + 8] = sv1;
        __syncthreads();

        // prefetch tile t0+64 (wrapped on last iter; values then unused)
        int tn = (t0 + 64) & (SS - 1);
        uint4 nv0 = *(const uint4*)(vsrc + tn);
        uint4 nv1 = *(const uint4*)(vsrc + tn + 8);
        bf16x8 nkf[4];
        #pragma unroll
        for (int tb = 0; tb < 4; tb++)
            nkf[tb] = *(const bf16x8*)(kfA + (size_t)(tn + tb * 16) * 8);

        // scores: D[t][q] = Kf.Qf via MFMA; exp2 -> bf16 P (per-wave LDS)
        #pragma unroll
        for (int tb = 0; tb < 4; tb++) {
            f32x4 sc = {};
            sc = __builtin_amdgcn_mfma_f32_16x16x32_bf16(kfr[tb], bfq, sc, 0, 0, 0);
            float p0 = EXP2F(sc[0]);
            float p1 = EXP2F(sc[1]);
            float p2 = EXP2F(sc[2]);
            float p3 = EXP2F(sc[3]);
            uint2 pw;
            pw.x = pack2bf(p0, p1);
            pw.y = pack2bf(p2, p3);
            *(uint2*)&ps[wave][l15][tb * 16 + l16 * 4] = pw;
        }

        // PV: D[q][d] += P . V^T ; l via ones column
        #pragma unroll
        for (int tk = 0; tk < 2; tk++) {
            bf16x8 ap = *(const bf16x8*)&ps[wave][l15][tk * 32 + l16 * 8];
            accl = __builtin_amdgcn_mfma_f32_16x16x32_bf16(ap, ones, accl, 0, 0, 0);
            #pragma unroll
            for (int nd = 0; nd < 4; nd++) {
                bf16x8 bv = *(const bf16x8*)&vt[nd * 16 + l15][tk * 32 + l16 * 8];
                acc[nd] = __builtin_amdgcn_mfma_f32_16x16x32_bf16(ap, bv, acc[nd], 0, 0, 0);
            }
        }

        sv0 = nv0; sv1 = nv1;
        #pragma unroll
        for (int tb = 0; tb < 4; tb++) kfr[tb] = nkf[tb];
    }

    // accl[r] = l for q = s0 + l16*4 + r — same row mapping as acc, no shuffles
    #pragma unroll
    for (int r = 0; r < 4; r++) {
        float linv = 1.f / accl[r];
        int q = s0 + l16 * 4 + r;
        size_t row = (size_t)(b * SS + q) * HH + h * HDD;
        #pragma unroll
        for (int nd = 0; nd < 4; nd++)
            attnb[row + nd * 16 + l15] = f2bf(acc[nd][r] * linv);
    }
}

extern "C" void kernel_launch(void* const* d_in, const int* in_sizes, int n_in,
                              void* d_out, int out_size, void* d_ws, size_t ws_size,
                              hipStream_t stream)
{
    const float* x  = (const float*)d_in[0];
    const float* Wq = (const float*)d_in[1];
    const float* Wk = (const float*)d_in[2];
    const float* Wv = (const float*)d_in[3];
    const float* Wo = (const float*)d_in[4];
    const float* bq = (const float*)d_in[5];
    const float* bk = (const float*)d_in[6];
    const float* bv = (const float*)d_in[7];
    const float* bo = (const float*)d_in[8];

    unsigned short* qfb   = (unsigned short*)d_ws;     // 524288
    unsigned short* kfb   = qfb + 524288;              // 524288
    unsigned short* xb    = kfb + 524288;              // 4194304 (aliased w/ attnb)
    unsigned short* attnb = xb;                        // alias: xb dead after fused_mid
    unsigned short* Wvb   = xb + 4194304;              // 1048576
    unsigned short* Wob   = Wvb + 1048576;             // 1048576
    unsigned short* Vt    = Wob + 1048576;             // 4194304
    unsigned short* wselb  = Vt + 4194304;             // 65536
    float*          bselws = (float*)(wselb + 65536);  // 64

    cvt_kernel<<<2112, 256, 0, stream>>>(x, Wv, Wo, Wq, Wk, bq, bk, xb, Wvb, Wob, wselb, bselws);
    fused_mid<<<1152, 256, 0, stream>>>(xb, Wvb, bv, Vt, wselb, bselws, qfb, kfb);
    attn_mfma<<<dim3(32, 32), 256, 0, stream>>>(qfb, kfb, Vt, attnb);
    gemm_out<<<dim3(16, 64), 256, 0, stream>>>(attnb, Wob, bo, (float*)d_out);
}

// Round 14
// 174.233 us; speedup vs baseline: 1.0280x; 1.0280x over previous
//
#include <hip/hip_runtime.h>
#include <hip/hip_bf16.h>

#define SS 2048
#define HH 1024
#define NHH 16
#define HDD 64

using f32x4  = __attribute__((ext_vector_type(4))) float;
using bf16x8 = __attribute__((ext_vector_type(8))) short;

#if __has_builtin(__builtin_amdgcn_exp2f)
#define EXP2F __builtin_amdgcn_exp2f
#else
#define EXP2F exp2f
#endif

__device__ __forceinline__ unsigned short f2bf(float f) {
    unsigned u = __builtin_bit_cast(unsigned, f);
    unsigned r = u + 0x7FFFu + ((u >> 16) & 1u);
    return (unsigned short)(r >> 16);
}

__device__ __forceinline__ unsigned bfround(float f) {
    unsigned u = __builtin_bit_cast(unsigned, f);
    return u + 0x7FFFu + ((u >> 16) & 1u);
}
// low16 = bf16(a), high16 = bf16(b) — one v_perm_b32
__device__ __forceinline__ unsigned pack2bf(float a, float b) {
    return __builtin_amdgcn_perm(bfround(b), bfround(a), 0x07060302u);
}

__device__ __forceinline__ void tetra(float t, float* c) {
    float a = 1.f / (1.f + __expf(-t));
    float na = 1.f - a;
    float nei = 1.f - (a + na);
    nei = fminf(fmaxf(nei, 0.f), 1.f);
    c[0] = a; c[1] = na; c[2] = a * na; c[3] = nei;
}

// ---------------- cvt: fp32 -> bf16 for x, Wv, Wo; blocks >=2048 gather Wsel ----------------
__global__ __launch_bounds__(256) void cvt_kernel(
    const float* __restrict__ x, const float* __restrict__ Wv, const float* __restrict__ Wo,
    const float* __restrict__ Wq, const float* __restrict__ Wk,
    const float* __restrict__ bq, const float* __restrict__ bk,
    unsigned short* __restrict__ xb, unsigned short* __restrict__ Wvb, unsigned short* __restrict__ Wob,
    unsigned short* __restrict__ wselb, float* __restrict__ bselws)
{
    if (blockIdx.x >= 2048) {
        int n = blockIdx.x - 2048;
        int h = n >> 2, q = n & 3;
        int rowIdx = h * HDD + ((q & 1) ? 2 : 0);
        const float* src  = (q & 2) ? Wk : Wq;
        const float* bsrc = (q & 2) ? bk : bq;
        int t = threadIdx.x;
        float4 v = *(const float4*)(src + (size_t)rowIdx * HH + t * 4);
        uint2 pk;
        pk.x = pack2bf(v.x, v.y);
        pk.y = pack2bf(v.z, v.w);
        *(uint2*)(wselb + (size_t)n * HH + t * 4) = pk;
        if (t == 0) bselws[n] = bsrc[rowIdx];
        return;
    }
    size_t gid = (size_t)blockIdx.x * 256 + threadIdx.x;
    size_t base = gid * 8;
    {
        float4 a = *(const float4*)(x + base);
        float4 b = *(const float4*)(x + base + 4);
        uint4 pk;
        pk.x = pack2bf(a.x, a.y);
        pk.y = pack2bf(a.z, a.w);
        pk.z = pack2bf(b.x, b.y);
        pk.w = pack2bf(b.z, b.w);
        *(uint4*)(xb + base) = pk;
    }
    if (base < 1048576) {
        float4 a = *(const float4*)(Wv + base);
        float4 b = *(const float4*)(Wv + base + 4);
        uint4 pk;
        pk.x = pack2bf(a.x, a.y);
        pk.y = pack2bf(a.z, a.w);
        pk.z = pack2bf(b.x, b.y);
        pk.w = pack2bf(b.z, b.w);
        *(uint4*)(Wvb + base) = pk;
        a = *(const float4*)(Wo + base);
        b = *(const float4*)(Wo + base + 4);
        pk.x = pack2bf(a.x, a.y);
        pk.y = pack2bf(a.z, a.w);
        pk.z = pack2bf(b.x, b.y);
        pk.w = pack2bf(b.z, b.w);
        *(uint4*)(Wob + base) = pk;
    }
}

// ---------------- GEMM body (R12 config: 128x64 tile, BK=64, reg-prefetch) ----------------
// OUT_MODE 0: fp32 row-major C. OUT_MODE 2: bf16 transposed into Vt[(bh*64+d)*SS + s].
template<int OUT_MODE>
__device__ __forceinline__ void gemm_body(unsigned char* smem,
    const unsigned short* __restrict__ A, const unsigned short* __restrict__ Bw,
    const float* __restrict__ bias, void* __restrict__ Cout, int bx, int by)
{
    auto As = (unsigned short (*)[72])smem;             // [128][72]
    auto Bs = (unsigned short (*)[72])(smem + 18432);   // [64][72]
    int tid = threadIdx.x;
    int wave = tid >> 6, lane = tid & 63;
    int l15 = lane & 15, l16 = lane >> 4;
    int wm = wave >> 1, wn = wave & 1;
    int m0 = by * 128, n0 = bx * 64;

    int ar = tid >> 1, aseg = (tid & 1) * 32;
    int br = tid >> 2, bseg = (tid & 3) * 16;
    const unsigned short* Ap = A + (size_t)(m0 + ar) * HH + aseg;
    const unsigned short* Bp = Bw + (size_t)(n0 + br) * HH + bseg;

    f32x4 acc[4][2] = {};

    uint4 a0 = *(const uint4*)(Ap);
    uint4 a1 = *(const uint4*)(Ap + 8);
    uint4 a2 = *(const uint4*)(Ap + 16);
    uint4 a3 = *(const uint4*)(Ap + 24);
    uint4 b0 = *(const uint4*)(Bp);
    uint4 b1 = *(const uint4*)(Bp + 8);

    for (int k0 = 0; k0 < HH; k0 += 64) {
        __syncthreads();
        *(uint4*)&As[ar][aseg]      = a0;
        *(uint4*)&As[ar][aseg + 8]  = a1;
        *(uint4*)&As[ar][aseg + 16] = a2;
        *(uint4*)&As[ar][aseg + 24] = a3;
        *(uint4*)&Bs[br][bseg]      = b0;
        *(uint4*)&Bs[br][bseg + 8]  = b1;
        __syncthreads();

        int kn = (k0 + 64) & (HH - 1);
        uint4 na0 = *(const uint4*)(Ap + kn);
        uint4 na1 = *(const uint4*)(Ap + kn + 8);
        uint4 na2 = *(const uint4*)(Ap + kn + 16);
        uint4 na3 = *(const uint4*)(Ap + kn + 24);
        uint4 nb0 = *(const uint4*)(Bp + kn);
        uint4 nb1 = *(const uint4*)(Bp + kn + 8);

        #pragma unroll
        for (int kk = 0; kk < 64; kk += 32) {
            bf16x8 af[4], bfr[2];
            #pragma unroll
            for (int mi = 0; mi < 4; mi++)
                af[mi] = *(const bf16x8*)&As[wm * 64 + mi * 16 + l15][kk + l16 * 8];
            #pragma unroll
            for (int ni = 0; ni < 2; ni++)
                bfr[ni] = *(const bf16x8*)&Bs[wn * 32 + ni * 16 + l15][kk + l16 * 8];
            #pragma unroll
            for (int mi = 0; mi < 4; mi++)
                #pragma unroll
                for (int ni = 0; ni < 2; ni++)
                    acc[mi][ni] = __builtin_amdgcn_mfma_f32_16x16x32_bf16(af[mi], bfr[ni], acc[mi][ni], 0, 0, 0);
        }
        a0 = na0; a1 = na1; a2 = na2; a3 = na3; b0 = nb0; b1 = nb1;
    }

    float bv[2];
    #pragma unroll
    for (int ni = 0; ni < 2; ni++)
        bv[ni] = bias[n0 + wn * 32 + ni * 16 + l15];

    #pragma unroll
    for (int mi = 0; mi < 4; mi++) {
        #pragma unroll
        for (int ni = 0; ni < 2; ni++) {
            int n = n0 + wn * 32 + ni * 16 + l15;
            if (OUT_MODE == 0) {
                #pragma unroll
                for (int r = 0; r < 4; r++) {
                    int m = m0 + wm * 64 + mi * 16 + l16 * 4 + r;
                    ((float*)Cout)[(size_t)m * HH + n] = acc[mi][ni][r] + bv[ni];
                }
            } else {
                int m = m0 + wm * 64 + mi * 16 + l16 * 4;
                int b = m >> 11, s = m & 2047;
                int h = n >> 6, d = n & 63;
                uint2 pk;
                pk.x = pack2bf(acc[mi][ni][0] + bv[ni], acc[mi][ni][1] + bv[ni]);
                pk.y = pack2bf(acc[mi][ni][2] + bv[ni], acc[mi][ni][3] + bv[ni]);
                *(uint2*)((unsigned short*)Cout + ((size_t)((b * NHH + h) * HDD + d)) * SS + s) = pk;
            }
        }
    }
}

// ---------------- qk body (R8 config: 32 m-rows, BK=64, exp2 scales) ----------------
__device__ __forceinline__ void qk_body(unsigned char* smem,
    const unsigned short* __restrict__ xb, const unsigned short* __restrict__ wselb,
    const float* __restrict__ bselws,
    unsigned short* __restrict__ qfb, unsigned short* __restrict__ kfb, int blk)
{
    auto xs = (unsigned short (*)[72])smem;             // [32][72]  (4608 B)
    auto ws = (unsigned short (*)[72])(smem + 4608);    // [64][72]  (9216 B)
    auto ys = (float (*)[68])(smem + 13824);            // [32][68]  (8704 B)
    int tid = threadIdx.x;
    int wave = tid >> 6, lane = tid & 63;
    int l15 = lane & 15, l16 = lane >> 4;
    int m0 = blk * 32;
    int n0w = wave * 16;

    int xr = tid >> 3, xseg = (tid & 7) * 8;
    int wr = tid >> 2, wseg = (tid & 3) * 16;
    const unsigned short* xp = xb + (size_t)(m0 + xr) * HH + xseg;
    const unsigned short* wp = wselb + (size_t)wr * HH + wseg;

    f32x4 acc[2] = {};

    uint4 xv  = *(const uint4*)(xp);
    uint4 wv0 = *(const uint4*)(wp);
    uint4 wv1 = *(const uint4*)(wp + 8);

    for (int k0 = 0; k0 < HH; k0 += 64) {
        __syncthreads();
        *(uint4*)&xs[xr][xseg] = xv;
        *(uint4*)&ws[wr][wseg]     = wv0;
        *(uint4*)&ws[wr][wseg + 8] = wv1;
        __syncthreads();

        int kn = (k0 + 64) & (HH - 1);
        uint4 nxv  = *(const uint4*)(xp + kn);
        uint4 nwv0 = *(const uint4*)(wp + kn);
        uint4 nwv1 = *(const uint4*)(wp + kn + 8);

        #pragma unroll
        for (int kk = 0; kk < 64; kk += 32) {
            bf16x8 bfr = *(const bf16x8*)&ws[n0w + l15][kk + l16 * 8];
            #pragma unroll
            for (int mi = 0; mi < 2; mi++) {
                bf16x8 af = *(const bf16x8*)&xs[mi * 16 + l15][kk + l16 * 8];
                acc[mi] = __builtin_amdgcn_mfma_f32_16x16x32_bf16(af, bfr, acc[mi], 0, 0, 0);
            }
        }
        xv = nxv; wv0 = nwv0; wv1 = nwv1;
    }

    float bias = bselws[n0w + l15];
    __syncthreads();
    #pragma unroll
    for (int mi = 0; mi < 2; mi++)
        #pragma unroll
        for (int r = 0; r < 4; r++)
            ys[mi * 16 + l16 * 4 + r][n0w + l15] = acc[mi][r] + bias;
    __syncthreads();

    #pragma unroll
    for (int pass = 0; pass < 2; pass++) {
        int ml = tid & 31;
        int h = (tid >> 5) + pass * 8;
        float4 y4 = *(const float4*)&ys[ml][h * 4];
        float qa[4], qb2[4], ka[4], kb2[4];
        tetra(y4.x, qa);
        tetra(y4.y, qb2);
        tetra(y4.z, ka);
        tetra(y4.w, kb2);
        int m = m0 + ml, b = m >> 11, s = m & 2047;
        size_t base = ((size_t)(b * NHH + h) * SS + s) * 8;
        const float sA = 0.18033688011112042f;   // 0.125 * log2(e)
        const float sB = 0.14426950408889634f;   // 0.1   * log2(e)
        uint4 qp, kp;
        qp.x = pack2bf(qa[0] * sA, qa[1] * sA);
        qp.y = pack2bf(qa[2] * sA, qa[3] * sA);
        qp.z = pack2bf(qb2[0] * sB, qb2[1] * sB);
        qp.w = pack2bf(qb2[2] * sB, qb2[3] * sB);
        kp.x = pack2bf(ka[0], ka[1]);
        kp.y = pack2bf(ka[2], ka[3]);
        kp.z = pack2bf(kb2[0], kb2[1]);
        kp.w = pack2bf(kb2[2], kb2[3]);
        *(uint4*)(qfb + base) = qp;
        *(uint4*)(kfb + base) = kp;
    }
}

// ---------------- fused mid kernel: blocks 0-511 = V-GEMM, 512-639 = qk ----------------
__global__ __launch_bounds__(256) void fused_mid(
    const unsigned short* __restrict__ xb,
    const unsigned short* __restrict__ Wvb, const float* __restrict__ bv,
    unsigned short* __restrict__ Vt,
    const unsigned short* __restrict__ wselb, const float* __restrict__ bselws,
    unsigned short* __restrict__ qfb, unsigned short* __restrict__ kfb)
{
    __shared__ __align__(16) unsigned char smem[27648];
    int id = blockIdx.x;
    if (id < 512)
        gemm_body<2>(smem, xb, Wvb, bv, Vt, id & 15, id >> 4);
    else
        qk_body(smem, xb, wselb, bselws, qfb, kfb, id - 512);
}

// ---------------- standalone O-projection GEMM ----------------
__global__ __launch_bounds__(256) void gemm_out(
    const unsigned short* __restrict__ A, const unsigned short* __restrict__ Bw,
    const float* __restrict__ bias, float* __restrict__ Cout)
{
    __shared__ __align__(16) unsigned char smem[27648];
    gemm_body<0>(smem, A, Bw, bias, Cout, blockIdx.x, blockIdx.y);
}

// ---------------- MFMA flash attention — double-buffered vt, ONE barrier per tile ----------------
// Block: one (b,h), 64 q (4 waves x 16 q). Tiles of 64 t. grid (32, 32) = 1024 blocks.
// Iter i: single sync; write tile i+1 into vt[(i+1)&1]; prefetch tile i+2; compute tile i from vt[i&1].
// Safety: any wave past sync_i has finished iter i-1's reads of vt[(i+1)&1]; writes of vt[i&1]
// (iter i+1) happen only after sync_{i+1}, which waits for iter-i readers.
__global__ __launch_bounds__(256) void attn_mfma(
    const unsigned short* __restrict__ qfb, const unsigned short* __restrict__ kfb,
    const unsigned short* __restrict__ Vt, unsigned short* __restrict__ attnb)
{
    __shared__ unsigned short vt[2][64][72];    // double-buffered V^T tile [d][t]
    __shared__ unsigned short ps[4][16][72];    // per-wave P [q][t]

    int tid = threadIdx.x;
    int wave = tid >> 6, lane = tid & 63;
    int l15 = lane & 15, l16 = lane >> 4;
    int bh = blockIdx.y, b = bh >> 4, h = bh & 15;
    int s0 = blockIdx.x * 64 + wave * 16;       // this wave's 16 q

    bf16x8 bfq = {0,0,0,0,0,0,0,0};
    if (l16 == 0)
        bfq = *(const bf16x8*)(qfb + ((size_t)bh * SS + s0 + l15) * 8);

    const short oneb = 0x3F80;                  // bf16 1.0
    bf16x8 ones = {oneb,oneb,oneb,oneb,oneb,oneb,oneb,oneb};

    const unsigned short* kfA = kfb + ((size_t)bh * SS + l15) * 8;
    int vd = tid >> 2, vseg = (tid & 3) * 16;
    const unsigned short* vsrc = Vt + ((size_t)bh * HDD + vd) * SS + vseg;

    f32x4 acc[4] = {};     // [nd] -> 16 q x 16 d each
    f32x4 accl = {};       // l via ones-column MFMA; row layout == acc rows

    // tile 0 straight into buf 0 (loop-top sync publishes it)
    {
        uint4 t0a = *(const uint4*)(vsrc);
        uint4 t0b = *(const uint4*)(vsrc + 8);
        *(uint4*)&vt[0][vd][vseg]     = t0a;
        *(uint4*)&vt[0][vd][vseg + 8] = t0b;
    }
    // prefetch tile 1 (V) and tile 0 (kf) into regs
    uint4 sv0 = *(const uint4*)(vsrc + 64);
    uint4 sv1 = *(const uint4*)(vsrc + 64 + 8);
    bf16x8 kfr[4];
    #pragma unroll
    for (int tb = 0; tb < 4; tb++)
        kfr[tb] = *(const bf16x8*)(kfA + (size_t)(tb * 16) * 8);

    for (int it = 0; it < 32; it++) {
        int t0 = it << 6;
        __syncthreads();

        // write tile it+1 into the other buffer
        int nb = (it + 1) & 1;
        *(uint4*)&vt[nb][vd][vseg]     = sv0;
        *(uint4*)&vt[nb][vd][vseg + 8] = sv1;

        // prefetch tile it+2 (V) and tile it+1 (kf), wrapped on tail (values then unused)
        int tv = (t0 + 128) & (SS - 1);
        uint4 nv0 = *(const uint4*)(vsrc + tv);
        uint4 nv1 = *(const uint4*)(vsrc + tv + 8);
        int tkf = (t0 + 64) & (SS - 1);
        bf16x8 nkf[4];
        #pragma unroll
        for (int tb = 0; tb < 4; tb++)
            nkf[tb] = *(const bf16x8*)(kfA + (size_t)(tkf + tb * 16) * 8);

        // scores for tile it: D[t][q] = Kf.Qf via MFMA; exp2 -> bf16 P (per-wave LDS)
        #pragma unroll
        for (int tb = 0; tb < 4; tb++) {
            f32x4 sc = {};
            sc = __builtin_amdgcn_mfma_f32_16x16x32_bf16(kfr[tb], bfq, sc, 0, 0, 0);
            float p0 = EXP2F(sc[0]);
            float p1 = EXP2F(sc[1]);
            float p2 = EXP2F(sc[2]);
            float p3 = EXP2F(sc[3]);
            uint2 pw;
            pw.x = pack2bf(p0, p1);
            pw.y = pack2bf(p2, p3);
            *(uint2*)&ps[wave][l15][tb * 16 + l16 * 4] = pw;
        }

        // PV for tile it from buf[it&1]: D[q][d] += P . V^T ; l via ones column
        int cb = it & 1;
        #pragma unroll
        for (int tk = 0; tk < 2; tk++) {
            bf16x8 ap = *(const bf16x8*)&ps[wave][l15][tk * 32 + l16 * 8];
            accl = __builtin_amdgcn_mfma_f32_16x16x32_bf16(ap, ones, accl, 0, 0, 0);
            #pragma unroll
            for (int nd = 0; nd < 4; nd++) {
                bf16x8 bv = *(const bf16x8*)&vt[cb][nd * 16 + l15][tk * 32 + l16 * 8];
                acc[nd] = __builtin_amdgcn_mfma_f32_16x16x32_bf16(ap, bv, acc[nd], 0, 0, 0);
            }
        }

        sv0 = nv0; sv1 = nv1;
        #pragma unroll
        for (int tb = 0; tb < 4; tb++) kfr[tb] = nkf[tb];
    }

    // accl[r] = l for q = s0 + l16*4 + r — same row mapping as acc, no shuffles
    #pragma unroll
    for (int r = 0; r < 4; r++) {
        float linv = 1.f / accl[r];
        int q = s0 + l16 * 4 + r;
        size_t row = (size_t)(b * SS + q) * HH + h * HDD;
        #pragma unroll
        for (int nd = 0; nd < 4; nd++)
            attnb[row + nd * 16 + l15] = f2bf(acc[nd][r] * linv);
    }
}

extern "C" void kernel_launch(void* const* d_in, const int* in_sizes, int n_in,
                              void* d_out, int out_size, void* d_ws, size_t ws_size,
                              hipStream_t stream)
{
    const float* x  = (const float*)d_in[0];
    const float* Wq = (const float*)d_in[1];
    const float* Wk = (const float*)d_in[2];
    const float* Wv = (const float*)d_in[3];
    const float* Wo = (const float*)d_in[4];
    const float* bq = (const float*)d_in[5];
    const float* bk = (const float*)d_in[6];
    const float* bv = (const float*)d_in[7];
    const float* bo = (const float*)d_in[8];

    unsigned short* qfb   = (unsigned short*)d_ws;     // 524288
    unsigned short* kfb   = qfb + 524288;              // 524288
    unsigned short* xb    = kfb + 524288;              // 4194304 (aliased w/ attnb)
    unsigned short* attnb = xb;                        // alias: xb dead after fused_mid
    unsigned short* Wvb   = xb + 4194304;              // 1048576
    unsigned short* Wob   = Wvb + 1048576;             // 1048576
    unsigned short* Vt    = Wob + 1048576;             // 4194304
    unsigned short* wselb  = Vt + 4194304;             // 65536
    float*          bselws = (float*)(wselb + 65536);  // 64

    cvt_kernel<<<2112, 256, 0, stream>>>(x, Wv, Wo, Wq, Wk, bq, bk, xb, Wvb, Wob, wselb, bselws);
    fused_mid<<<640, 256, 0, stream>>>(xb, Wvb, bv, Vt, wselb, bselws, qfb, kfb);
    attn_mfma<<<dim3(32, 32), 256, 0, stream>>>(qfb, kfb, Vt, attnb);
    gemm_out<<<dim3(16, 32), 256, 0, stream>>>(attnb, Wob, bo, (float*)d_out);
}

// Round 15
// 173.870 us; speedup vs baseline: 1.0302x; 1.0021x over previous
//
#include <hip/hip_runtime.h>
#include <hip/hip_bf16.h>

#define SS 2048
#define HH 1024
#define NHH 16
#define HDD 64

using f32x4  = __attribute__((ext_vector_type(4))) float;
using bf16x8 = __attribute__((ext_vector_type(8))) short;

#if __has_builtin(__builtin_amdgcn_exp2f)
#define EXP2F __builtin_amdgcn_exp2f
#else
#define EXP2F exp2f
#endif

__device__ __forceinline__ unsigned short f2bf(float f) {
    unsigned u = __builtin_bit_cast(unsigned, f);
    unsigned r = u + 0x7FFFu + ((u >> 16) & 1u);
    return (unsigned short)(r >> 16);
}

__device__ __forceinline__ unsigned bfround(float f) {
    unsigned u = __builtin_bit_cast(unsigned, f);
    return u + 0x7FFFu + ((u >> 16) & 1u);
}
// low16 = bf16(a) RNE, high16 = bf16(b) RNE — one v_perm_b32 after rounding
__device__ __forceinline__ unsigned pack2bf(float a, float b) {
    return __builtin_amdgcn_perm(bfround(b), bfround(a), 0x07060302u);
}
// truncating pack: raw high shorts, single v_perm_b32 (bias cancels in softmax ratio)
__device__ __forceinline__ unsigned pack2bf_trunc(float a, float b) {
    return __builtin_amdgcn_perm(__builtin_bit_cast(unsigned, b),
                                 __builtin_bit_cast(unsigned, a), 0x07060302u);
}

__device__ __forceinline__ void tetra(float t, float* c) {
    float a = 1.f / (1.f + __expf(-t));
    float na = 1.f - a;
    float nei = 1.f - (a + na);
    nei = fminf(fmaxf(nei, 0.f), 1.f);
    c[0] = a; c[1] = na; c[2] = a * na; c[3] = nei;
}

// ---------------- cvt: fp32 -> bf16 for x, Wv, Wo; blocks >=2048 gather Wsel ----------------
__global__ __launch_bounds__(256) void cvt_kernel(
    const float* __restrict__ x, const float* __restrict__ Wv, const float* __restrict__ Wo,
    const float* __restrict__ Wq, const float* __restrict__ Wk,
    const float* __restrict__ bq, const float* __restrict__ bk,
    unsigned short* __restrict__ xb, unsigned short* __restrict__ Wvb, unsigned short* __restrict__ Wob,
    unsigned short* __restrict__ wselb, float* __restrict__ bselws)
{
    if (blockIdx.x >= 2048) {
        int n = blockIdx.x - 2048;
        int h = n >> 2, q = n & 3;
        int rowIdx = h * HDD + ((q & 1) ? 2 : 0);
        const float* src  = (q & 2) ? Wk : Wq;
        const float* bsrc = (q & 2) ? bk : bq;
        int t = threadIdx.x;
        float4 v = *(const float4*)(src + (size_t)rowIdx * HH + t * 4);
        uint2 pk;
        pk.x = pack2bf(v.x, v.y);
        pk.y = pack2bf(v.z, v.w);
        *(uint2*)(wselb + (size_t)n * HH + t * 4) = pk;
        if (t == 0) bselws[n] = bsrc[rowIdx];
        return;
    }
    size_t gid = (size_t)blockIdx.x * 256 + threadIdx.x;
    size_t base = gid * 8;
    {
        float4 a = *(const float4*)(x + base);
        float4 b = *(const float4*)(x + base + 4);
        uint4 pk;
        pk.x = pack2bf(a.x, a.y);
        pk.y = pack2bf(a.z, a.w);
        pk.z = pack2bf(b.x, b.y);
        pk.w = pack2bf(b.z, b.w);
        *(uint4*)(xb + base) = pk;
    }
    if (base < 1048576) {
        float4 a = *(const float4*)(Wv + base);
        float4 b = *(const float4*)(Wv + base + 4);
        uint4 pk;
        pk.x = pack2bf(a.x, a.y);
        pk.y = pack2bf(a.z, a.w);
        pk.z = pack2bf(b.x, b.y);
        pk.w = pack2bf(b.z, b.w);
        *(uint4*)(Wvb + base) = pk;
        a = *(const float4*)(Wo + base);
        b = *(const float4*)(Wo + base + 4);
        pk.x = pack2bf(a.x, a.y);
        pk.y = pack2bf(a.z, a.w);
        pk.z = pack2bf(b.x, b.y);
        pk.w = pack2bf(b.z, b.w);
        *(uint4*)(Wob + base) = pk;
    }
}

// ---------------- GEMM body (R12 config: 128x64 tile, BK=64, reg-prefetch) ----------------
// OUT_MODE 0: fp32 row-major C. OUT_MODE 2: bf16 transposed into Vt[(bh*64+d)*SS + s].
template<int OUT_MODE>
__device__ __forceinline__ void gemm_body(unsigned char* smem,
    const unsigned short* __restrict__ A, const unsigned short* __restrict__ Bw,
    const float* __restrict__ bias, void* __restrict__ Cout, int bx, int by)
{
    auto As = (unsigned short (*)[72])smem;             // [128][72]
    auto Bs = (unsigned short (*)[72])(smem + 18432);   // [64][72]
    int tid = threadIdx.x;
    int wave = tid >> 6, lane = tid & 63;
    int l15 = lane & 15, l16 = lane >> 4;
    int wm = wave >> 1, wn = wave & 1;
    int m0 = by * 128, n0 = bx * 64;

    int ar = tid >> 1, aseg = (tid & 1) * 32;
    int br = tid >> 2, bseg = (tid & 3) * 16;
    const unsigned short* Ap = A + (size_t)(m0 + ar) * HH + aseg;
    const unsigned short* Bp = Bw + (size_t)(n0 + br) * HH + bseg;

    f32x4 acc[4][2] = {};

    uint4 a0 = *(const uint4*)(Ap);
    uint4 a1 = *(const uint4*)(Ap + 8);
    uint4 a2 = *(const uint4*)(Ap + 16);
    uint4 a3 = *(const uint4*)(Ap + 24);
    uint4 b0 = *(const uint4*)(Bp);
    uint4 b1 = *(const uint4*)(Bp + 8);

    for (int k0 = 0; k0 < HH; k0 += 64) {
        __syncthreads();
        *(uint4*)&As[ar][aseg]      = a0;
        *(uint4*)&As[ar][aseg + 8]  = a1;
        *(uint4*)&As[ar][aseg + 16] = a2;
        *(uint4*)&As[ar][aseg + 24] = a3;
        *(uint4*)&Bs[br][bseg]      = b0;
        *(uint4*)&Bs[br][bseg + 8]  = b1;
        __syncthreads();

        int kn = (k0 + 64) & (HH - 1);
        uint4 na0 = *(const uint4*)(Ap + kn);
        uint4 na1 = *(const uint4*)(Ap + kn + 8);
        uint4 na2 = *(const uint4*)(Ap + kn + 16);
        uint4 na3 = *(const uint4*)(Ap + kn + 24);
        uint4 nb0 = *(const uint4*)(Bp + kn);
        uint4 nb1 = *(const uint4*)(Bp + kn + 8);

        #pragma unroll
        for (int kk = 0; kk < 64; kk += 32) {
            bf16x8 af[4], bfr[2];
            #pragma unroll
            for (int mi = 0; mi < 4; mi++)
                af[mi] = *(const bf16x8*)&As[wm * 64 + mi * 16 + l15][kk + l16 * 8];
            #pragma unroll
            for (int ni = 0; ni < 2; ni++)
                bfr[ni] = *(const bf16x8*)&Bs[wn * 32 + ni * 16 + l15][kk + l16 * 8];
            #pragma unroll
            for (int mi = 0; mi < 4; mi++)
                #pragma unroll
                for (int ni = 0; ni < 2; ni++)
                    acc[mi][ni] = __builtin_amdgcn_mfma_f32_16x16x32_bf16(af[mi], bfr[ni], acc[mi][ni], 0, 0, 0);
        }
        a0 = na0; a1 = na1; a2 = na2; a3 = na3; b0 = nb0; b1 = nb1;
    }

    float bv[2];
    #pragma unroll
    for (int ni = 0; ni < 2; ni++)
        bv[ni] = bias[n0 + wn * 32 + ni * 16 + l15];

    #pragma unroll
    for (int mi = 0; mi < 4; mi++) {
        #pragma unroll
        for (int ni = 0; ni < 2; ni++) {
            int n = n0 + wn * 32 + ni * 16 + l15;
            if (OUT_MODE == 0) {
                #pragma unroll
                for (int r = 0; r < 4; r++) {
                    int m = m0 + wm * 64 + mi * 16 + l16 * 4 + r;
                    ((float*)Cout)[(size_t)m * HH + n] = acc[mi][ni][r] + bv[ni];
                }
            } else {
                int m = m0 + wm * 64 + mi * 16 + l16 * 4;
                int b = m >> 11, s = m & 2047;
                int h = n >> 6, d = n & 63;
                uint2 pk;
                pk.x = pack2bf(acc[mi][ni][0] + bv[ni], acc[mi][ni][1] + bv[ni]);
                pk.y = pack2bf(acc[mi][ni][2] + bv[ni], acc[mi][ni][3] + bv[ni]);
                *(uint2*)((unsigned short*)Cout + ((size_t)((b * NHH + h) * HDD + d)) * SS + s) = pk;
            }
        }
    }
}

// ---------------- qk body (R8 config: 32 m-rows, BK=64, exp2 scales) ----------------
__device__ __forceinline__ void qk_body(unsigned char* smem,
    const unsigned short* __restrict__ xb, const unsigned short* __restrict__ wselb,
    const float* __restrict__ bselws,
    unsigned short* __restrict__ qfb, unsigned short* __restrict__ kfb, int blk)
{
    auto xs = (unsigned short (*)[72])smem;             // [32][72]  (4608 B)
    auto ws = (unsigned short (*)[72])(smem + 4608);    // [64][72]  (9216 B)
    auto ys = (float (*)[68])(smem + 13824);            // [32][68]  (8704 B)
    int tid = threadIdx.x;
    int wave = tid >> 6, lane = tid & 63;
    int l15 = lane & 15, l16 = lane >> 4;
    int m0 = blk * 32;
    int n0w = wave * 16;

    int xr = tid >> 3, xseg = (tid & 7) * 8;
    int wr = tid >> 2, wseg = (tid & 3) * 16;
    const unsigned short* xp = xb + (size_t)(m0 + xr) * HH + xseg;
    const unsigned short* wp = wselb + (size_t)wr * HH + wseg;

    f32x4 acc[2] = {};

    uint4 xv  = *(const uint4*)(xp);
    uint4 wv0 = *(const uint4*)(wp);
    uint4 wv1 = *(const uint4*)(wp + 8);

    for (int k0 = 0; k0 < HH; k0 += 64) {
        __syncthreads();
        *(uint4*)&xs[xr][xseg] = xv;
        *(uint4*)&ws[wr][wseg]     = wv0;
        *(uint4*)&ws[wr][wseg + 8] = wv1;
        __syncthreads();

        int kn = (k0 + 64) & (HH - 1);
        uint4 nxv  = *(const uint4*)(xp + kn);
        uint4 nwv0 = *(const uint4*)(wp + kn);
        uint4 nwv1 = *(const uint4*)(wp + kn + 8);

        #pragma unroll
        for (int kk = 0; kk < 64; kk += 32) {
            bf16x8 bfr = *(const bf16x8*)&ws[n0w + l15][kk + l16 * 8];
            #pragma unroll
            for (int mi = 0; mi < 2; mi++) {
                bf16x8 af = *(const bf16x8*)&xs[mi * 16 + l15][kk + l16 * 8];
                acc[mi] = __builtin_amdgcn_mfma_f32_16x16x32_bf16(af, bfr, acc[mi], 0, 0, 0);
            }
        }
        xv = nxv; wv0 = nwv0; wv1 = nwv1;
    }

    float bias = bselws[n0w + l15];
    __syncthreads();
    #pragma unroll
    for (int mi = 0; mi < 2; mi++)
        #pragma unroll
        for (int r = 0; r < 4; r++)
            ys[mi * 16 + l16 * 4 + r][n0w + l15] = acc[mi][r] + bias;
    __syncthreads();

    #pragma unroll
    for (int pass = 0; pass < 2; pass++) {
        int ml = tid & 31;
        int h = (tid >> 5) + pass * 8;
        float4 y4 = *(const float4*)&ys[ml][h * 4];
        float qa[4], qb2[4], ka[4], kb2[4];
        tetra(y4.x, qa);
        tetra(y4.y, qb2);
        tetra(y4.z, ka);
        tetra(y4.w, kb2);
        int m = m0 + ml, b = m >> 11, s = m & 2047;
        size_t base = ((size_t)(b * NHH + h) * SS + s) * 8;
        const float sA = 0.18033688011112042f;   // 0.125 * log2(e)
        const float sB = 0.14426950408889634f;   // 0.1   * log2(e)
        uint4 qp, kp;
        qp.x = pack2bf(qa[0] * sA, qa[1] * sA);
        qp.y = pack2bf(qa[2] * sA, qa[3] * sA);
        qp.z = pack2bf(qb2[0] * sB, qb2[1] * sB);
        qp.w = pack2bf(qb2[2] * sB, qb2[3] * sB);
        kp.x = pack2bf(ka[0], ka[1]);
        kp.y = pack2bf(ka[2], ka[3]);
        kp.z = pack2bf(kb2[0], kb2[1]);
        kp.w = pack2bf(kb2[2], kb2[3]);
        *(uint4*)(qfb + base) = qp;
        *(uint4*)(kfb + base) = kp;
    }
}

// ---------------- fused mid kernel: blocks 0-511 = V-GEMM, 512-639 = qk ----------------
__global__ __launch_bounds__(256) void fused_mid(
    const unsigned short* __restrict__ xb,
    const unsigned short* __restrict__ Wvb, const float* __restrict__ bv,
    unsigned short* __restrict__ Vt,
    const unsigned short* __restrict__ wselb, const float* __restrict__ bselws,
    unsigned short* __restrict__ qfb, unsigned short* __restrict__ kfb)
{
    __shared__ __align__(16) unsigned char smem[27648];
    int id = blockIdx.x;
    if (id < 512)
        gemm_body<2>(smem, xb, Wvb, bv, Vt, id & 15, id >> 4);
    else
        qk_body(smem, xb, wselb, bselws, qfb, kfb, id - 512);
}

// ---------------- standalone O-projection GEMM ----------------
__global__ __launch_bounds__(256) void gemm_out(
    const unsigned short* __restrict__ A, const unsigned short* __restrict__ Bw,
    const float* __restrict__ bias, float* __restrict__ Cout)
{
    __shared__ __align__(16) unsigned char smem[27648];
    gemm_body<0>(smem, A, Bw, bias, Cout, blockIdx.x, blockIdx.y);
}

// ---------------- MFMA flash attention — dbuf vt, one barrier/tile, truncated P pack ----------------
// Block: one (b,h), 64 q (4 waves x 16 q). Tiles of 64 t. grid (32, 32) = 1024 blocks.
__global__ __launch_bounds__(256) void attn_mfma(
    const unsigned short* __restrict__ qfb, const unsigned short* __restrict__ kfb,
    const unsigned short* __restrict__ Vt, unsigned short* __restrict__ attnb)
{
    __shared__ unsigned short vt[2][64][72];    // double-buffered V^T tile [d][t]
    __shared__ unsigned short ps[4][16][72];    // per-wave P [q][t]

    int tid = threadIdx.x;
    int wave = tid >> 6, lane = tid & 63;
    int l15 = lane & 15, l16 = lane >> 4;
    int bh = blockIdx.y, b = bh >> 4, h = bh & 15;
    int s0 = blockIdx.x * 64 + wave * 16;       // this wave's 16 q

    bf16x8 bfq = {0,0,0,0,0,0,0,0};
    if (l16 == 0)
        bfq = *(const bf16x8*)(qfb + ((size_t)bh * SS + s0 + l15) * 8);

    const short oneb = 0x3F80;                  // bf16 1.0
    bf16x8 ones = {oneb,oneb,oneb,oneb,oneb,oneb,oneb,oneb};

    const unsigned short* kfA = kfb + ((size_t)bh * SS + l15) * 8;
    int vd = tid >> 2, vseg = (tid & 3) * 16;
    const unsigned short* vsrc = Vt + ((size_t)bh * HDD + vd) * SS + vseg;

    f32x4 acc[4] = {};     // [nd] -> 16 q x 16 d each
    f32x4 accl = {};       // l via ones-column MFMA over the SAME truncated P (bias cancels)

    // tile 0 straight into buf 0 (loop-top sync publishes it)
    {
        uint4 t0a = *(const uint4*)(vsrc);
        uint4 t0b = *(const uint4*)(vsrc + 8);
        *(uint4*)&vt[0][vd][vseg]     = t0a;
        *(uint4*)&vt[0][vd][vseg + 8] = t0b;
    }
    // prefetch tile 1 (V) and tile 0 (kf) into regs
    uint4 sv0 = *(const uint4*)(vsrc + 64);
    uint4 sv1 = *(const uint4*)(vsrc + 64 + 8);
    bf16x8 kfr[4];
    #pragma unroll
    for (int tb = 0; tb < 4; tb++)
        kfr[tb] = *(const bf16x8*)(kfA + (size_t)(tb * 16) * 8);

    for (int it = 0; it < 32; it++) {
        int t0 = it << 6;
        __syncthreads();

        // write tile it+1 into the other buffer
        int nb = (it + 1) & 1;
        *(uint4*)&vt[nb][vd][vseg]     = sv0;
        *(uint4*)&vt[nb][vd][vseg + 8] = sv1;

        // prefetch tile it+2 (V) and tile it+1 (kf), wrapped on tail (values then unused)
        int tv = (t0 + 128) & (SS - 1);
        uint4 nv0 = *(const uint4*)(vsrc + tv);
        uint4 nv1 = *(const uint4*)(vsrc + tv + 8);
        int tkf = (t0 + 64) & (SS - 1);
        bf16x8 nkf[4];
        #pragma unroll
        for (int tb = 0; tb < 4; tb++)
            nkf[tb] = *(const bf16x8*)(kfA + (size_t)(tkf + tb * 16) * 8);

        // scores for tile it: D[t][q] = Kf.Qf via MFMA; exp2 -> truncated bf16 P
        #pragma unroll
        for (int tb = 0; tb < 4; tb++) {
            f32x4 sc = {};
            sc = __builtin_amdgcn_mfma_f32_16x16x32_bf16(kfr[tb], bfq, sc, 0, 0, 0);
            float p0 = EXP2F(sc[0]);
            float p1 = EXP2F(sc[1]);
            float p2 = EXP2F(sc[2]);
            float p3 = EXP2F(sc[3]);
            uint2 pw;
            pw.x = pack2bf_trunc(p0, p1);
            pw.y = pack2bf_trunc(p2, p3);
            *(uint2*)&ps[wave][l15][tb * 16 + l16 * 4] = pw;
        }

        // PV for tile it from buf[it&1]: D[q][d] += P . V^T ; l via ones column
        int cb = it & 1;
        #pragma unroll
        for (int tk = 0; tk < 2; tk++) {
            bf16x8 ap = *(const bf16x8*)&ps[wave][l15][tk * 32 + l16 * 8];
            accl = __builtin_amdgcn_mfma_f32_16x16x32_bf16(ap, ones, accl, 0, 0, 0);
            #pragma unroll
            for (int nd = 0; nd < 4; nd++) {
                bf16x8 bv = *(const bf16x8*)&vt[cb][nd * 16 + l15][tk * 32 + l16 * 8];
                acc[nd] = __builtin_amdgcn_mfma_f32_16x16x32_bf16(ap, bv, acc[nd], 0, 0, 0);
            }
        }

        sv0 = nv0; sv1 = nv1;
        #pragma unroll
        for (int tb = 0; tb < 4; tb++) kfr[tb] = nkf[tb];
    }

    // accl[r] = l for q = s0 + l16*4 + r — same row mapping as acc, no shuffles
    #pragma unroll
    for (int r = 0; r < 4; r++) {
        float linv = 1.f / accl[r];
        int q = s0 + l16 * 4 + r;
        size_t row = (size_t)(b * SS + q) * HH + h * HDD;
        #pragma unroll
        for (int nd = 0; nd < 4; nd++)
            attnb[row + nd * 16 + l15] = f2bf(acc[nd][r] * linv);
    }
}

extern "C" void kernel_launch(void* const* d_in, const int* in_sizes, int n_in,
                              void* d_out, int out_size, void* d_ws, size_t ws_size,
                              hipStream_t stream)
{
    const float* x  = (const float*)d_in[0];
    const float* Wq = (const float*)d_in[1];
    const float* Wk = (const float*)d_in[2];
    const float* Wv = (const float*)d_in[3];
    const float* Wo = (const float*)d_in[4];
    const float* bq = (const float*)d_in[5];
    const float* bk = (const float*)d_in[6];
    const float* bv = (const float*)d_in[7];
    const float* bo = (const float*)d_in[8];

    unsigned short* qfb   = (unsigned short*)d_ws;     // 524288
    unsigned short* kfb   = qfb + 524288;              // 524288
    unsigned short* xb    = kfb + 524288;              // 4194304 (aliased w/ attnb)
    unsigned short* attnb = xb;                        // alias: xb dead after fused_mid
    unsigned short* Wvb   = xb + 4194304;              // 1048576
    unsigned short* Wob   = Wvb + 1048576;             // 1048576
    unsigned short* Vt    = Wob + 1048576;             // 4194304
    unsigned short* wselb  = Vt + 4194304;             // 65536
    float*          bselws = (float*)(wselb + 65536);  // 64

    cvt_kernel<<<2112, 256, 0, stream>>>(x, Wv, Wo, Wq, Wk, bq, bk, xb, Wvb, Wob, wselb, bselws);
    fused_mid<<<640, 256, 0, stream>>>(xb, Wvb, bv, Vt, wselb, bselws, qfb, kfb);
    attn_mfma<<<dim3(32, 32), 256, 0, stream>>>(qfb, kfb, Vt, attnb);
    gemm_out<<<dim3(16, 32), 256, 0, stream>>>(attnb, Wob, bo, (float*)d_out);
}